// Round 9
// baseline (217.011 us; speedup 1.0000x reference)
//
#include <hip/hip_runtime.h>
#include <math.h>

#define T_ 2048
#define NH_ 8
#define HD_ 128

typedef unsigned short u16;
typedef short bf16x8 __attribute__((ext_vector_type(8)));
typedef _Float16 f16x8 __attribute__((ext_vector_type(8)));
typedef float f32x4 __attribute__((ext_vector_type(4)));

union FH { _Float16 h; u16 u; };

__device__ __forceinline__ u16 f2h(float f)
{
    FH c; c.h = (_Float16)f; return c.u;
}
__device__ __forceinline__ float h2f(u16 v)
{
    FH c; c.u = v; return (float)c.h;
}
// fp32 -> (hi, lo) fp16 split; a ~= hi + lo, rel err ~2^-22
__device__ __forceinline__ void split1h(float f, u16& h, u16& l)
{
    h = f2h(f);
    l = f2h(f - h2f(h));
}

__device__ __forceinline__ u16 f2bf(float f)
{
    unsigned u = __float_as_uint(f);
    return (u16)((u + 0x7FFFu + ((u >> 16) & 1u)) >> 16);
}
__device__ __forceinline__ float bf2f(u16 h)
{
    return __uint_as_float(((unsigned)h) << 16);
}

#define GLD16(SRC, DST) __builtin_amdgcn_global_load_lds( \
    (const __attribute__((address_space(1))) unsigned int*)(SRC), \
    (__attribute__((address_space(3))) unsigned int*)(DST), 16, 0, 0)

// packed layout (lane-linear: per-lane SRC + wave-uniform LDS dst + lane*16B):
// offset(row, k; Kd) = (row>>6)*(Kd*64) + (k>>5)*2048 + ((k>>3)&3)*512
//                    + (row&63)*8 + (k&7)

// ---------------------------------------------------------------------------
// cvt_in: merged input-only work.
//   blocks 0..4095    : x fp32 -> fp16 packed
//   blocks 4096..6143 : enc_q/enc_v -> packed weights
//   blocks 6144..7167 : decoder -> packed weights
//   blocks 7168..7679 : hebbmat (MhT per head, bf16)
// ---------------------------------------------------------------------------
__global__ __launch_bounds__(256) void cvt_in(const float* __restrict__ x,
                                              const float* __restrict__ enc_q,
                                              const float* __restrict__ enc_v,
                                              const float* __restrict__ dec,
                                              const float* __restrict__ hU,
                                              const float* __restrict__ hV,
                                              u16* __restrict__ xh,
                                              u16* __restrict__ WTh,
                                              u16* __restrict__ WdT,
                                              u16* __restrict__ MhT)
{
    __shared__ u16 tH[32][33];
    const int bid = blockIdx.x;
    if (bid < 4096) {
        int i = (bid * 256 + threadIdx.x) * 4;
        int m = i >> 10, k = i & 1023;
        float4 v = *(const float4*)&x[i];
        ushort4 hv = {f2h(v.x), f2h(v.y), f2h(v.z), f2h(v.w)};
        long o = (long)(m >> 6) * 65536 + (k >> 5) * 2048
               + ((k >> 3) & 3) * 512 + (m & 63) * 8 + (k & 7);
        *(ushort4*)&xh[o] = hv;
    } else if (bid < 6144) {
        int rb = bid - 4096;
        int bx = rb & 31, by = (rb >> 5) & 31, bz = rb >> 10;
        const float* Bw = bz ? enc_v : enc_q;
        const int nofs = bz << 10;
        const int tid = threadIdx.x;
        const int tx = tid & 31, ty = tid >> 5;
        const int k0 = bx * 32, c0 = by * 32;
        #pragma unroll
        for (int r = 0; r < 4; ++r) {
            int k = k0 + ty * 4 + r;
            int c = c0 + tx;
            float v = Bw[(long)(c >> 7) * 131072 + (long)k * 128 + (c & 127)];
            tH[ty * 4 + r][tx] = f2h(v);
        }
        __syncthreads();
        #pragma unroll
        for (int r = 0; r < 4; ++r) {
            int n = nofs + c0 + ty * 4 + r;
            int k = k0 + tx;
            long o = (long)(n >> 6) * 65536 + (k >> 5) * 2048
                   + ((k >> 3) & 3) * 512 + (n & 63) * 8 + (k & 7);
            WTh[o] = tH[tx][ty * 4 + r];
        }
    } else if (bid < 7168) {
        int rb = bid - 6144;
        int bx = rb & 31, by = rb >> 5;
        const int tid = threadIdx.x;
        const int tx = tid & 31, ty = tid >> 5;
        const int k0 = bx * 32, c0 = by * 32;
        #pragma unroll
        for (int r = 0; r < 4; ++r) {
            int k = k0 + ty * 4 + r;
            int c = c0 + tx;
            tH[ty * 4 + r][tx] = f2h(dec[(long)k * 1024 + c]);
        }
        __syncthreads();
        #pragma unroll
        for (int r = 0; r < 4; ++r) {
            int n = c0 + ty * 4 + r;
            int k = k0 + tx;
            long o = (long)(n >> 6) * 65536 + (k >> 5) * 2048
                   + ((k >> 3) & 3) * 512 + (n & 63) * 8 + (k & 7);
            WdT[o] = tH[tx][ty * 4 + r];
        }
    } else {
        int gid = (bid - 7168) * 256 + threadIdx.x;
        int h = gid >> 14;
        int rem = gid & 16383;
        int e = rem >> 7;
        int f = rem & 127;
        float a = 0.f;
        #pragma unroll
        for (int r = 0; r < 32; ++r)
            a += hU[(h * 128 + f) * 32 + r] * hV[(h * 32 + r) * 128 + e];
        MhT[(h * 128 + e) * 128 + f] = f2bf(a);
    }
}

// ---------------------------------------------------------------------------
// gemm_qv v15: 128x256 tile, single fp16, BLOCK-SHARED double-buffered LDS
// staging via global_load_lds (m97/G15 pattern).  Wave-private v14 loaded
// each A strip 2x and each B strip 2x; shared staging loads each strip ONCE
// per block: L1 traffic 48->24 KB and LDS-port 96->72 KB per block-ktile,
// zero staging VGPRs.  One __syncthreads per k-tile; compiler's pre-barrier
// vmcnt(0) drain publishes the prefetched tile.  Fragment/MFMA order is
// identical to v14 -> bit-identical output.
// LDS strips: [0..1]=A rows (m0,m0+64), [2..5]=B cols (n0..n0+255 by 64).
// ---------------------------------------------------------------------------
__global__ __launch_bounds__(256, 1) void gemm_qv(
    const u16* __restrict__ Ah, const u16* __restrict__ Bh,
    float* __restrict__ Qf, u16* __restrict__ Vh,
    float* __restrict__ Ps, float* __restrict__ Ps8, int Kd)
{
    __shared__ __align__(16) u16 S[2][6][2048];   // 48 KB

    const int tid  = threadIdx.x;
    const int w    = tid >> 6;
    const int lane = tid & 63;

    const int id   = blockIdx.x;
    const int m0   = (id & 31) * 128;
    const int n0   = (id >> 5) * 256;

    const int mw   = (w & 1) * 64, nw = (w >> 1) * 128;
    const int mr   = lane & 15, quad = lane >> 4;

    const long sstr = (long)Kd * 64;           // u16 per 64-row strip
    const u16* gA = Ah + (long)(m0 >> 6) * sstr + lane * 8;
    const u16* gB = Bh + (long)(n0 >> 6) * sstr + lane * 8;

    f32x4 acc[4][8] = {};

    // 24 wave-ops per k-tile (4 waves x 6): op o -> strip s=o>>2, quarter q=o&3
#define STAGE(KT, BUF) do { long t = (long)(KT) * 2048;                        \
    _Pragma("unroll")                                                          \
    for (int u = 0; u < 6; ++u) {                                              \
        int o = w * 6 + u;                                                     \
        int s = o >> 2, q = o & 3;                                             \
        const u16* g = (s < 2 ? gA + (long)s * sstr                            \
                              : gB + (long)(s - 2) * sstr) + t + q * 512;      \
        GLD16(g, &S[BUF][s][q * 512]);                                         \
    } } while (0)

    const u16* WA  = &S[0][w & 1][0];
    const u16* WB0 = &S[0][2 + ((w >> 1) << 1)][0];
    const int  bufstep = 6 * 2048;             // u16 per buffer

    auto compute = [&](int buf) {
        const u16* A  = WA  + buf * bufstep;
        const u16* B0 = WB0 + buf * bufstep;
        f16x8 fah[4], fbh[8];
        #pragma unroll
        for (int i = 0; i < 4; ++i)
            fah[i] = *(const f16x8*)(A + quad * 512 + (i * 16 + mr) * 8);
        #pragma unroll
        for (int j = 0; j < 8; ++j)
            fbh[j] = *(const f16x8*)(B0 + ((j < 4) ? 0 : 2048)
                                     + quad * 512 + ((j & 3) * 16 + mr) * 8);
        #pragma unroll
        for (int i = 0; i < 4; ++i)
            #pragma unroll
            for (int j = 0; j < 8; ++j)
                acc[i][j] = __builtin_amdgcn_mfma_f32_16x16x32_f16(fah[i], fbh[j], acc[i][j], 0, 0, 0);
    };

    const int NT = Kd >> 5;                    // 32
    STAGE(0, 0);
    __syncthreads();                           // vmcnt(0) drain -> buf0 ready
    for (int kt = 0; kt < NT; ++kt) {
        if (kt + 1 < NT) STAGE(kt + 1, (kt + 1) & 1);
        compute(kt & 1);
        __syncthreads();                       // publishes kt+1, frees kt
    }
#undef STAGE

    if (n0 < 1024) {
        // Q half: relu -> fp32 write + fused sig partials
        #pragma unroll
        for (int i = 0; i < 4; ++i)
            #pragma unroll
            for (int j = 0; j < 8; ++j)
                #pragma unroll
                for (int r = 0; r < 4; ++r) {
                    float v = fmaxf(acc[i][j][r], 0.f);
                    acc[i][j][r] = v;
                    int row = m0 + mw + i * 16 + quad * 4 + r;
                    int col = n0 + nw + j * 16 + mr;
                    Qf[(long)row * 1024 + col] = v;
                }
        int slot = (id & 31) * 2 + (w & 1);
        #pragma unroll
        for (int j = 0; j < 8; ++j) {
            float ps = 0.f, p8 = 0.f;
            #pragma unroll
            for (int i = 0; i < 4; ++i) {
                #pragma unroll
                for (int r = 0; r < 4; ++r) ps += acc[i][j][r];
                if ((quad & 1) == 0) p8 += acc[i][j][0];   // row%8==0 rows
            }
            ps += __shfl_xor(ps, 16, 64); ps += __shfl_xor(ps, 32, 64);
            p8 += __shfl_xor(p8, 16, 64); p8 += __shfl_xor(p8, 32, 64);
            if (quad == 0) {
                int col = n0 + nw + j * 16 + mr;
                Ps [slot * 1024 + col] = ps;
                Ps8[slot * 1024 + col] = p8;
            }
        }
    } else {
        // V half: relu -> fp16 PAIR layout: (e, e+64) adjacent
        #pragma unroll
        for (int i = 0; i < 4; ++i)
            #pragma unroll
            for (int j = 0; j < 8; ++j)
                #pragma unroll
                for (int r = 0; r < 4; ++r) {
                    float v = fmaxf(acc[i][j][r], 0.f);
                    int row = m0 + mw + i * 16 + quad * 4 + r;
                    int vcol = n0 - 1024 + nw + j * 16 + mr;
                    int pa = (vcol & ~127) + ((vcol & 63) * 2) + ((vcol >> 6) & 1);
                    Vh[(long)row * 1024 + pa] = f2h(v);
                }
    }
}

// ---------------------------------------------------------------------------
// gemm_dec v15: 128x128 tile, block-shared double-buffered gload_lds staging.
// LDS strips: [0..1]=A rows, [2..3]=B cols.  16 wave-ops per k-tile.
// ---------------------------------------------------------------------------
__global__ __launch_bounds__(256, 1) void gemm_dec(
    const u16* __restrict__ Ah, const u16* __restrict__ Bh,
    float* __restrict__ C, int N, int Kd)
{
    __shared__ __align__(16) u16 S[2][4][2048];   // 32 KB

    const int tid  = threadIdx.x;
    const int w    = tid >> 6;
    const int lane = tid & 63;

    const int id   = blockIdx.x;
    const int m0   = (((id & 7) << 2) + ((id >> 3) & 3)) * 128;
    const int n0   = (id >> 5) * 128;

    const int mw   = (w & 1) * 64, nw = (w >> 1) * 64;
    const int mr   = lane & 15, quad = lane >> 4;

    const long sstr = (long)Kd * 64;
    const u16* gA = Ah + (long)(m0 >> 6) * sstr + lane * 8;
    const u16* gB = Bh + (long)(n0 >> 6) * sstr + lane * 8;

    f32x4 acc[4][4] = {};

#define STAGE(KT, BUF) do { long t = (long)(KT) * 2048;                        \
    _Pragma("unroll")                                                          \
    for (int u = 0; u < 4; ++u) {                                              \
        int o = w * 4 + u;                                                     \
        int s = o >> 2, q = o & 3;                                             \
        const u16* g = (s < 2 ? gA + (long)s * sstr                            \
                              : gB + (long)(s - 2) * sstr) + t + q * 512;      \
        GLD16(g, &S[BUF][s][q * 512]);                                         \
    } } while (0)

    const u16* WA = &S[0][w & 1][0];
    const u16* WB = &S[0][2 + (w >> 1)][0];
    const int  bufstep = 4 * 2048;

    auto compute = [&](int buf) {
        const u16* A = WA + buf * bufstep;
        const u16* B = WB + buf * bufstep;
        f16x8 fah[4], fbh[4];
        #pragma unroll
        for (int i = 0; i < 4; ++i) {
            int ro = quad * 512 + (i * 16 + mr) * 8;
            fah[i] = *(const f16x8*)(A + ro);
            fbh[i] = *(const f16x8*)(B + ro);
        }
        #pragma unroll
        for (int i = 0; i < 4; ++i)
            #pragma unroll
            for (int j = 0; j < 4; ++j)
                acc[i][j] = __builtin_amdgcn_mfma_f32_16x16x32_f16(fah[i], fbh[j], acc[i][j], 0, 0, 0);
    };

    const int NT = Kd >> 5;
    STAGE(0, 0);
    __syncthreads();
    for (int kt = 0; kt < NT; ++kt) {
        if (kt + 1 < NT) STAGE(kt + 1, (kt + 1) & 1);
        compute(kt & 1);
        __syncthreads();
    }
#undef STAGE

    #pragma unroll
    for (int i = 0; i < 4; ++i)
        #pragma unroll
        for (int j = 0; j < 4; ++j)
            #pragma unroll
            for (int r = 0; r < 4; ++r) {
                int row = m0 + mw + i * 16 + quad * 4 + r;
                int col = n0 + nw + j * 16 + mr;
                C[(long)row * N + col] = acc[i][j][r];
            }
}

// ---------------------------------------------------------------------------
// qu_stage v14: fused metric finish + Q->Qbf/U/|u|^2 (unchanged).
// ---------------------------------------------------------------------------
__global__ __launch_bounds__(256) void qu_stage(const float* __restrict__ Qf,
                                                const float* __restrict__ Pm2,
                                                const float* __restrict__ b2,
                                                const float* __restrict__ base,
                                                u16* __restrict__ Qbf,
                                                u16* __restrict__ Uh, u16* __restrict__ Ul,
                                                float* __restrict__ nArr)
{
    __shared__ float sMe[128];
    const int tid = threadIdx.x;
    const int bh  = blockIdx.x >> 8;          // 256 blocks per bh
    if (tid < 128) {
        int b = bh >> 3;
        int c = (bh & 7) * 128 + tid;
        float a = b2[c];
        #pragma unroll
        for (int kc = 0; kc < 16; ++kc)
            a += Pm2[(b * 16 + kc) * 1024 + c];
        float mv = base[c] + 0.1f * a;
        sMe[tid] = fmaxf(mv, 0.f) + log1pf(expf(-fabsf(mv)));
    }
    __syncthreads();

    int gid4 = (blockIdx.x * 256 + tid) * 4;   // over 2*8*2048*128
    int e4 = gid4 & 127;
    int t  = (gid4 >> 7) & 2047;
    int b  = bh >> 3, h = bh & 7;
    float4 q = *(const float4*)&Qf[((long)(b * 2048 + t)) * 1024 + h * 128 + e4];
    ushort4 qo = {f2bf(q.x), f2bf(q.y), f2bf(q.z), f2bf(q.w)};
    *(ushort4*)&Qbf[((long)(b * 2048 + t)) * 1024 + h * 128 + e4] = qo;

    float4 m = *(const float4*)&sMe[e4];
    float ux = sqrtf(m.x) * q.x, uy = sqrtf(m.y) * q.y;
    float uz = sqrtf(m.z) * q.z, uw = sqrtf(m.w) * q.w;
    u16 h0, l0, h1, l1, h2, l2, h3, l3;
    split1h(ux, h0, l0); split1h(uy, h1, l1);
    split1h(uz, h2, l2); split1h(uw, h3, l3);
    ushort4 hv = {h0, h1, h2, h3}, lv = {l0, l1, l2, l3};
    *(ushort4*)&Uh[gid4] = hv;
    *(ushort4*)&Ul[gid4] = lv;
    float ps = ux * ux + uy * uy + uz * uz + uw * uw;
    #pragma unroll
    for (int mm = 16; mm; mm >>= 1) ps += __shfl_xor(ps, mm, 64);
    if ((tid & 31) == 0) nArr[gid4 >> 7] = ps;
}

// ---------------------------------------------------------------------------
// hebdist: merged heb_gemm (blocks 0..255) + dist_gemm (blocks 256..767).
// ---------------------------------------------------------------------------
__global__ __launch_bounds__(256, 1) void hebdist(
    const u16* __restrict__ Qbf, const u16* __restrict__ MhT,
    u16* __restrict__ HEBbf,
    const u16* __restrict__ Uh, const u16* __restrict__ Ul,
    const float* __restrict__ nArr, float* __restrict__ band)
{
    __shared__ __align__(16) u16 sA[4][128][8], sB[4][128][8];      // heb
    __shared__ __align__(16) u16 sAh[4][64][8],  sAl[4][64][8];     // dist
    __shared__ __align__(16) u16 sBh[4][128][8], sBl[4][128][8];
    __shared__ float epi[4][16][128];

    const int tid  = threadIdx.x;
    const int w    = tid >> 6;
    const int lane = tid & 63;
    const int mr   = lane & 15, quad = lane >> 4;

    if (blockIdx.x < 256) {
        // ---------------- heb_gemm body ----------------
        const int m0 = (blockIdx.x & 31) * 128;
        const int h  = blockIdx.x >> 5;
        const int mw = w * 32;
        const u16* Bm = MhT + h * 16384;

        f32x4 acc[2][8] = {};

        for (int k0 = 0; k0 < 128; k0 += 32) {
            #pragma unroll
            for (int u = 0; u < 4; ++u) {
                int c = (w & 1) * 4 + u;
                int kq = c >> 1, half = c & 1;
                const u16* src; u16* dst; long gofs;
                if (w < 2) {
                    src = Qbf;
                    dst = &sA[0][0][0] + kq * 1024 + half * 512;
                    gofs = (long)(m0 + half * 64 + lane) * 1024 + h * 128 + k0 + kq * 8;
                } else {
                    src = Bm;
                    dst = &sB[0][0][0] + kq * 1024 + half * 512;
                    gofs = (long)(half * 64 + lane) * 128 + k0 + kq * 8;
                }
                GLD16(src + gofs, dst);
            }
            __syncthreads();

            bf16x8 fa[2], fb[8];
            #pragma unroll
            for (int i = 0; i < 2; ++i)
                fa[i] = *(const bf16x8*)&sA[quad][mw + i * 16 + mr][0];
            #pragma unroll
            for (int j = 0; j < 8; ++j)
                fb[j] = *(const bf16x8*)&sB[quad][j * 16 + mr][0];
            #pragma unroll
            for (int i = 0; i < 2; ++i)
                #pragma unroll
                for (int j = 0; j < 8; ++j)
                    acc[i][j] = __builtin_amdgcn_mfma_f32_16x16x32_bf16(fa[i], fb[j], acc[i][j], 0, 0, 0);
            __syncthreads();
        }

        #pragma unroll
        for (int i = 0; i < 2; ++i)
            #pragma unroll
            for (int j = 0; j < 8; ++j)
                #pragma unroll
                for (int r = 0; r < 4; ++r) {
                    int row = m0 + mw + i * 16 + quad * 4 + r;
                    int col = h * 128 + j * 16 + mr;
                    HEBbf[(long)row * 1024 + col] = f2bf(acc[i][j][r]);
                }
    } else {
        // ---------------- dist_gemm body ----------------
        const int bid  = blockIdx.x - 256;
        const int tile = bid & 31, bh = bid >> 5;
        const int t0   = tile * 64;
        const long ub  = (long)bh * 2048 * 128;

        const u16 *s0, *s1, *s2, *s3, *s4, *s5;
        u16 *d0, *d1, *d2, *d3, *d4, *d5;
        long o0, o1, o2, o3, o4, o5;
        {
            auto mk = [&](int i, const u16*& src, u16*& dst, long& ofs) {
                int c = i * 256 + tid;
                if (c < 512) {
                    int row = c & 63, kq = (c >> 6) & 3;
                    src = (c < 256) ? Uh : Ul;
                    ofs = ub + (long)(t0 + row) * 128 + kq * 8;
                    dst = ((c < 256) ? &sAh[0][0][0] : &sAl[0][0][0]) + kq * 512 + row * 8;
                } else {
                    int cb = c - 512;
                    int row = cb & 127, kq = (cb >> 7) & 3;
                    src = (cb < 512) ? Uh : Ul;
                    ofs = ub + (long)(t0 - 64 + row) * 128 + kq * 8;
                    dst = ((cb < 512) ? &sBh[0][0][0] : &sBl[0][0][0]) + kq * 1024 + row * 8;
                }
            };
            mk(0, s0, d0, o0); mk(1, s1, d1, o1); mk(2, s2, d2, o2);
            mk(3, s3, d3, o3); mk(4, s4, d4, o4); mk(5, s5, d5, o5);
        }

        f32x4 acc[8] = {};
        uint4 g0, g1, g2, g3, g4, g5;
        g0 = *(const uint4*)(s0 + o0); g1 = *(const uint4*)(s1 + o1);
        g2 = *(const uint4*)(s2 + o2); g3 = *(const uint4*)(s3 + o3);
        g4 = *(const uint4*)(s4 + o4); g5 = *(const uint4*)(s5 + o5);

        for (int k0 = 0; k0 < 128; k0 += 32) {
            *(uint4*)d0 = g0; *(uint4*)d1 = g1; *(uint4*)d2 = g2;
            *(uint4*)d3 = g3; *(uint4*)d4 = g4; *(uint4*)d5 = g5;
            __syncthreads();

            if (k0 + 32 < 128) {
                int kn = k0 + 32;
                g0 = *(const uint4*)(s0 + o0 + kn); g1 = *(const uint4*)(s1 + o1 + kn);
                g2 = *(const uint4*)(s2 + o2 + kn); g3 = *(const uint4*)(s3 + o3 + kn);
                g4 = *(const uint4*)(s4 + o4 + kn); g5 = *(const uint4*)(s5 + o5 + kn);
            }

            f16x8 fah = *(const f16x8*)&sAh[quad][w * 16 + mr][0];
            f16x8 fal = *(const f16x8*)&sAl[quad][w * 16 + mr][0];
            #pragma unroll
            for (int j = 0; j < 8; ++j) {
                f16x8 fbh = *(const f16x8*)&sBh[quad][j * 16 + mr][0];
                f16x8 fbl = *(const f16x8*)&sBl[quad][j * 16 + mr][0];
                acc[j] = __builtin_amdgcn_mfma_f32_16x16x32_f16(fah, fbh, acc[j], 0, 0, 0);
                acc[j] = __builtin_amdgcn_mfma_f32_16x16x32_f16(fah, fbl, acc[j], 0, 0, 0);
                acc[j] = __builtin_amdgcn_mfma_f32_16x16x32_f16(fal, fbh, acc[j], 0, 0, 0);
            }
            __syncthreads();
        }

        #pragma unroll
        for (int j = 0; j < 8; ++j)
            #pragma unroll
            for (int r = 0; r < 4; ++r)
                epi[w][quad * 4 + r][j * 16 + mr] = acc[j][r];
        __syncthreads();

        const float* nb = nArr + (long)bh * 2048;
        #pragma unroll
        for (int i = 0; i < 16; ++i) {
            int id = i * 256 + tid;
            int tl = id >> 6, j = id & 63;
            int t  = t0 + tl;
            int r  = t - j;
            int rc = r < 0 ? 0 : r;
            int rl = tl - j + 64;
            float S  = epi[tl >> 4][tl & 15][rl];
            float d2 = nb[t] + nb[rc] - 2.0f * S;
            band[((long)bh * 2048 + t) * 64 + j] = d2;
        }
    }
}

// ---------------------------------------------------------------------------
// mlp chain (unchanged).
// ---------------------------------------------------------------------------
__global__ __launch_bounds__(256) void mlp1_part(const float* __restrict__ Ps,
                                                 const float* __restrict__ Ps8,
                                                 const float* __restrict__ w1,
                                                 float* __restrict__ Pm)
{
    __shared__ float ssig[32];
    int tid = threadIdx.x;
    int o  = blockIdx.x * 256 + tid;           // 0..511
    int b  = blockIdx.y;
    int kc = blockIdx.z;                       // 0..31
    int k0 = kc * 32;
    if (tid < 32) {
        int k = k0 + tid;
        float s = 0.f, s8 = 0.f;
        #pragma unroll
        for (int ms = 0; ms < 32; ++ms) {
            long po = ((long)(b * 32 + ms)) * 1024 + k;
            s  += Ps[po];
            s8 += Ps8[po];
        }
        ssig[tid] = s * (1.0f / 2048.0f) + 0.5f * s8 * (1.0f / 256.0f);
    }
    __syncthreads();
    float a = 0.f;
    #pragma unroll 8
    for (int kk = 0; kk < 32; ++kk)
        a += ssig[kk] * w1[(long)(k0 + kk) * 512 + o];
    Pm[((b * 32) + kc) * 512 + o] = a;
}

__global__ __launch_bounds__(256) void mlp2_part(const float* __restrict__ Pm1,
                                                 const float* __restrict__ b1,
                                                 const float* __restrict__ w2,
                                                 float* __restrict__ Pm)
{
    __shared__ float sH[32];
    int tid = threadIdx.x;
    int c  = blockIdx.x * 256 + tid;           // 0..1023
    int b  = blockIdx.y;
    int kc = blockIdx.z;                       // 0..15
    int k0 = kc * 32;
    if (tid < 32) {
        int o = k0 + tid;
        float a = b1[o];
        #pragma unroll
        for (int kcc = 0; kcc < 32; ++kcc)
            a += Pm1[(b * 32 + kcc) * 512 + o];
        sH[tid] = 0.5f * a * (1.0f + erff(a * 0.70710678118f));
    }
    __syncthreads();
    float a = 0.f;
    #pragma unroll 8
    for (int kk = 0; kk < 32; ++kk)
        a += sH[kk] * w2[(long)(k0 + kk) * 1024 + c];
    Pm[((b * 16) + kc) * 1024 + c] = a;
}

// ---------------------------------------------------------------------------
// Context kernel v9: paired V gather, packed-key bitonic top-32, CT fp16.
// ---------------------------------------------------------------------------
__global__ __launch_bounds__(256) void context_k(
    const float* __restrict__ Qf, const u16* __restrict__ Vh,
    const float* __restrict__ band, const u16* __restrict__ HEBbf,
    u16* __restrict__ CTh)
{
    __shared__ float wv[4][32];
    __shared__ int   wi[4][32];

    const int w    = threadIdx.x >> 6;
    const int lane = threadIdx.x & 63;
    const int gw   = blockIdx.x * 4 + w;
    const int h    = gw & 7;
    const int bt   = gw >> 3;
    const int t    = bt & (T_ - 1);
    const int b    = bt >> 11;
    const int bh   = b * 8 + h;

    const long qrow  = (long)bt * 1024 + h * 128;
    const long hrow  = (long)bt * 1024 + h * 128;

    float q0 = Qf[qrow + lane], q1 = Qf[qrow + 64 + lane];
    float ss = q0 * q0 + q1 * q1;
    #pragma unroll
    for (int s = 32; s; s >>= 1) ss += __shfl_xor(ss, s, 64);
    const float qn  = sqrtf(ss);
    const float inv = 1.0f / fmaxf(qn, 1e-12f);

    int je = lane < t ? lane : t;
    float d2v = (je == 0) ? 0.f
              : band[((long)bh * 2048 + t) * 64 + je];
    float d2f = fmaxf(d2v, 0.f) + 1e-8f;                 // > 0
    unsigned kb = (__float_as_uint(d2f) & 0xFFFFFFC0u) | (unsigned)lane;

    // bitonic construction to k=32: lanes 0-31 ascending, 32-63 descending
    #pragma unroll
    for (int k = 2; k <= 32; k <<= 1)
        #pragma unroll
        for (int s = k >> 1; s >= 1; s >>= 1) {
            unsigned ok = __shfl_xor(kb, s, 64);
            bool takeMin = (((lane & k) == 0) == ((lane & s) == 0));
            if ((ok < kb) == takeMin) kb = ok;           // keys unique: no ties
        }
    // cross-half min: lanes 0-31 now hold the 32 smallest (set, unsorted)
    {
        unsigned ok = __shfl_xor(kb, 32, 64);
        kb = ok < kb ? ok : kb;
    }

    int jj = kb & 63;
    float wexp = 0.f;
    if (lane < 32)
        wexp = expf(-sqrtf(__uint_as_float(kb & 0xFFFFFFC0u)));
    float tot = wexp;
    #pragma unroll
    for (int s = 32; s; s >>= 1) tot += __shfl_xor(tot, s, 64);
    float wn = wexp / (tot + 1e-8f);
    if (lane < 32) {
        wv[w][lane] = wn;
        int ii = t - jj; if (ii < 0) ii = 0;
        wi[w][lane] = ii;
    }

    float c0 = 0.f, c1 = 0.f;
    #pragma unroll 8
    for (int k = 0; k < 32; ++k) {
        float wk = wv[w][k];
        long vb = ((long)(b * T_ + wi[w][k])) * 1024 + h * 128 + lane * 2;
        unsigned vv = *(const unsigned*)&Vh[vb];
        c0 += wk * h2f((u16)(vv & 0xffffu));      // element e = lane
        c1 += wk * h2f((u16)(vv >> 16));          // element e = lane + 64
    }

    if (qn > 0.2f) {
        float s = 0.1f * inv;
        c0 += s * bf2f(HEBbf[hrow + lane]);
        c1 += s * bf2f(HEBbf[hrow + 64 + lane]);
    }

    // packed CT write (Kd=1024 -> strip stride 65536): col c = h*128+lane(+64)
    int c0c = h * 128 + lane, c1c = c0c + 64;
    long po0 = (long)(bt >> 6) * 65536 + (c0c >> 5) * 2048
             + ((c0c >> 3) & 3) * 512 + (bt & 63) * 8 + (c0c & 7);
    long po1 = (long)(bt >> 6) * 65536 + (c1c >> 5) * 2048
             + ((c1c >> 3) & 3) * 512 + (bt & 63) * 8 + (c1c & 7);
    CTh[po0] = f2h(q0 * c0);
    CTh[po1] = f2h(q1 * c1);
}

// ---------------------------------------------------------------------------
extern "C" void kernel_launch(void* const* d_in, const int* in_sizes, int n_in,
                              void* d_out, int out_size, void* d_ws, size_t ws_size,
                              hipStream_t stream)
{
    const float* x     = (const float*)d_in[0];
    const float* enc_q = (const float*)d_in[1];
    const float* enc_v = (const float*)d_in[2];
    const float* w1    = (const float*)d_in[3];
    const float* b1    = (const float*)d_in[4];
    const float* w2    = (const float*)d_in[5];
    const float* b2    = (const float*)d_in[6];
    const float* base  = (const float*)d_in[7];
    const float* hU    = (const float*)d_in[8];
    const float* hV    = (const float*)d_in[9];
    const float* dec   = (const float*)d_in[10];
    float* out = (float*)d_out;
    float* ws  = (float*)d_ws;

    // ws (fp32-offset map), peak 13205504 floats = 50.4 MB (< 51 MB budget):
    float* Qf   = ws;                       // [0, 4194304)       gemm_qv -> qu/context
    u16*  Vhp   = (u16*)(ws + 4194304);     // [4194304, 6291456) pair-layout V
    float* band = ws + 6291456;             // [6291456, 8388608) dist -> context
    u16*  wTh   = (u16*)(ws + 8388608);     // enc weights, dead after gemm_qv
    u16*  Ulp   = (u16*)(ws + 8388608);     // U lo, after wTh/Ps dead
    float* Ps   = ws + 9961472;             // sig partials, dead after mlp1
    float* Ps8  = ws + 10027008;
    u16*  Uhp   = (u16*)(ws + 10485760);    // U hi [10485760, 12582912)
    u16*  CTh   = (u16*)(ws + 8388608);     // packed CT, after Ul dead
    u16*  MhT   = (u16*)(ws + 12582912);    // [12582912, 12648448)
    float* nA   = ws + 12648448;            // [12648448, 12681216)
    u16*  wdTh  = (u16*)(ws + 12681216);    // [12681216, 13205504) decoder W
    u16*  xh    = (u16*)d_out;              // packed x staging in d_out
    u16*  Qbf   = (u16*)d_out;              // after xh dead; dead after hebdist
    u16*  HEBbf = (u16*)d_out + 4194304;    // float [2097152, 4194304)
    float* Pm1  = (float*)d_out + 2097152;  // dead before hebdist writes HEBbf
    float* Pm2  = (float*)d_out + 2129920;

    // 1. all input-only conversions (x, enc, dec, hebb matrices)
    cvt_in<<<7680, 256, 0, stream>>>(x, enc_q, enc_v, dec, hU, hV,
                                     xh, wTh, wdTh, MhT);

    // 2. QV = relu(x @ [enc_q | enc_v]) -> Q fp32 + V fp16 pairs + sig partials
    gemm_qv<<<256, 256, 0, stream>>>(xh, wTh, Qf, Vhp, Ps, Ps8, 1024);

    // 3-4. metric MLP split-K
    mlp1_part<<<dim3(2, 2, 32), 256, 0, stream>>>(Ps, Ps8, w1, Pm1);
    mlp2_part<<<dim3(4, 2, 16), 256, 0, stream>>>(Pm1, b1, w2, Pm2);

    // 5. Q -> Qbf/U/|u|^2 with fused metric finish
    qu_stage<<<4096, 256, 0, stream>>>(Qf, Pm2, b2, base, Qbf, Uhp, Ulp, nA);

    // 6. merged HEB gemm + banded distance gemm
    hebdist<<<768, 256, 0, stream>>>(Qbf, MhT, HEBbf, Uhp, Ulp, nA, band);

    // 7. top-32 select + weighted V gather + Hebb term -> CT fp16 packed
    context_k<<<8192, 256, 0, stream>>>(Qf, Vhp, band, HEBbf, CTh);

    // 8. out = CT @ decoder
    gemm_dec<<<256, 256, 0, stream>>>(CTh, wdTh, out, 1024, 1024);
}

// Round 10
// 208.685 us; speedup vs baseline: 1.0399x; 1.0399x over previous
//
#include <hip/hip_runtime.h>
#include <math.h>

#define T_ 2048
#define NH_ 8
#define HD_ 128

typedef unsigned short u16;
typedef short bf16x8 __attribute__((ext_vector_type(8)));
typedef _Float16 f16x8 __attribute__((ext_vector_type(8)));
typedef float f32x4 __attribute__((ext_vector_type(4)));

union FH { _Float16 h; u16 u; };

__device__ __forceinline__ u16 f2h(float f)
{
    FH c; c.h = (_Float16)f; return c.u;
}
__device__ __forceinline__ float h2f(u16 v)
{
    FH c; c.u = v; return (float)c.h;
}
// fp32 -> (hi, lo) fp16 split; a ~= hi + lo, rel err ~2^-22
__device__ __forceinline__ void split1h(float f, u16& h, u16& l)
{
    h = f2h(f);
    l = f2h(f - h2f(h));
}

__device__ __forceinline__ u16 f2bf(float f)
{
    unsigned u = __float_as_uint(f);
    return (u16)((u + 0x7FFFu + ((u >> 16) & 1u)) >> 16);
}
__device__ __forceinline__ float bf2f(u16 h)
{
    return __uint_as_float(((unsigned)h) << 16);
}

#define GLD16(SRC, DST) __builtin_amdgcn_global_load_lds( \
    (const __attribute__((address_space(1))) unsigned int*)(SRC), \
    (__attribute__((address_space(3))) unsigned int*)(DST), 16, 0, 0)

// packed layout (lane-linear on both staging sides):
// offset(row, k; Kd) = (row>>6)*(Kd*64) + (k>>5)*2048 + ((k>>3)&3)*512
//                    + (row&63)*8 + (k&7)

// ---------------------------------------------------------------------------
// cvt_in: merged input-only work.
//   blocks 0..4095    : x fp32 -> fp16 packed
//   blocks 4096..6143 : enc_q/enc_v -> packed weights
//   blocks 6144..7167 : decoder -> packed weights
//   blocks 7168..7679 : hebbmat (MhT per head, bf16)
// ---------------------------------------------------------------------------
__global__ __launch_bounds__(256) void cvt_in(const float* __restrict__ x,
                                              const float* __restrict__ enc_q,
                                              const float* __restrict__ enc_v,
                                              const float* __restrict__ dec,
                                              const float* __restrict__ hU,
                                              const float* __restrict__ hV,
                                              u16* __restrict__ xh,
                                              u16* __restrict__ WTh,
                                              u16* __restrict__ WdT,
                                              u16* __restrict__ MhT)
{
    __shared__ u16 tH[32][33];
    const int bid = blockIdx.x;
    if (bid < 4096) {
        int i = (bid * 256 + threadIdx.x) * 4;
        int m = i >> 10, k = i & 1023;
        float4 v = *(const float4*)&x[i];
        ushort4 hv = {f2h(v.x), f2h(v.y), f2h(v.z), f2h(v.w)};
        long o = (long)(m >> 6) * 65536 + (k >> 5) * 2048
               + ((k >> 3) & 3) * 512 + (m & 63) * 8 + (k & 7);
        *(ushort4*)&xh[o] = hv;
    } else if (bid < 6144) {
        int rb = bid - 4096;
        int bx = rb & 31, by = (rb >> 5) & 31, bz = rb >> 10;
        const float* Bw = bz ? enc_v : enc_q;
        const int nofs = bz << 10;
        const int tid = threadIdx.x;
        const int tx = tid & 31, ty = tid >> 5;
        const int k0 = bx * 32, c0 = by * 32;
        #pragma unroll
        for (int r = 0; r < 4; ++r) {
            int k = k0 + ty * 4 + r;
            int c = c0 + tx;
            float v = Bw[(long)(c >> 7) * 131072 + (long)k * 128 + (c & 127)];
            tH[ty * 4 + r][tx] = f2h(v);
        }
        __syncthreads();
        #pragma unroll
        for (int r = 0; r < 4; ++r) {
            int n = nofs + c0 + ty * 4 + r;
            int k = k0 + tx;
            long o = (long)(n >> 6) * 65536 + (k >> 5) * 2048
                   + ((k >> 3) & 3) * 512 + (n & 63) * 8 + (k & 7);
            WTh[o] = tH[tx][ty * 4 + r];
        }
    } else if (bid < 7168) {
        int rb = bid - 6144;
        int bx = rb & 31, by = rb >> 5;
        const int tid = threadIdx.x;
        const int tx = tid & 31, ty = tid >> 5;
        const int k0 = bx * 32, c0 = by * 32;
        #pragma unroll
        for (int r = 0; r < 4; ++r) {
            int k = k0 + ty * 4 + r;
            int c = c0 + tx;
            tH[ty * 4 + r][tx] = f2h(dec[(long)k * 1024 + c]);
        }
        __syncthreads();
        #pragma unroll
        for (int r = 0; r < 4; ++r) {
            int n = c0 + ty * 4 + r;
            int k = k0 + tx;
            long o = (long)(n >> 6) * 65536 + (k >> 5) * 2048
                   + ((k >> 3) & 3) * 512 + (n & 63) * 8 + (k & 7);
            WdT[o] = tH[tx][ty * 4 + r];
        }
    } else {
        int gid = (bid - 7168) * 256 + threadIdx.x;
        int h = gid >> 14;
        int rem = gid & 16383;
        int e = rem >> 7;
        int f = rem & 127;
        float a = 0.f;
        #pragma unroll
        for (int r = 0; r < 32; ++r)
            a += hU[(h * 128 + f) * 32 + r] * hV[(h * 32 + r) * 128 + e];
        MhT[(h * 128 + e) * 128 + f] = f2bf(a);
    }
}

// ---------------------------------------------------------------------------
// gemm_qv v14 (REVERTED from v15 — block-shared staging regressed +6.5us,
// same as v13's async: every barrier-per-ktile scheme loses to the
// barrier-free wave-private reg-staged pipeline).  128x256 tile, fp16.
// Epilogue: Q fp32 + sig partials; V fp16 PAIR layout ((e,e+64) adjacent).
// ---------------------------------------------------------------------------
__global__ __launch_bounds__(256, 1) void gemm_qv(
    const u16* __restrict__ Ah, const u16* __restrict__ Bh,
    float* __restrict__ Qf, u16* __restrict__ Vh,
    float* __restrict__ Ps, float* __restrict__ Ps8, int Kd)
{
    __shared__ __align__(16) u16 S[4][6144];   // 12 KB per wave

    const int tid  = threadIdx.x;
    const int w    = tid >> 6;
    const int lane = tid & 63;

    const int id   = blockIdx.x;
    const int m0   = (id & 31) * 128;
    const int n0   = (id >> 5) * 256;

    const int mw   = (w & 1) * 64, nw = (w >> 1) * 128;
    const int mr   = lane & 15, quad = lane >> 4;

    const long sstr = (long)Kd * 64;           // u16 per 64-row strip
    const u16* gAh = Ah + (long)((m0 + mw) >> 6) * sstr;
    const u16* gB0 = Bh + (long)((n0 + nw) >> 6) * sstr;
    const u16* gB1 = gB0 + sstr;

    u16* W = &S[w][0];   // [A:4][B0:4][B1:4] x [kq][row64][8] u16

    f32x4 acc[4][8] = {};
    uint4 a0, a1, a2, a3;
    uint4 b0, b1, b2, b3, b4, b5, b6, b7;

#define LOADG(KT) do { long t = (long)(KT) * 2048 + lane * 8;                        \
    a0 = *(const uint4*)(gAh + t +    0); a1 = *(const uint4*)(gAh + t +  512);      \
    a2 = *(const uint4*)(gAh + t + 1024); a3 = *(const uint4*)(gAh + t + 1536);      \
    b0 = *(const uint4*)(gB0 + t +    0); b1 = *(const uint4*)(gB0 + t +  512);      \
    b2 = *(const uint4*)(gB0 + t + 1024); b3 = *(const uint4*)(gB0 + t + 1536);      \
    b4 = *(const uint4*)(gB1 + t +    0); b5 = *(const uint4*)(gB1 + t +  512);      \
    b6 = *(const uint4*)(gB1 + t + 1024); b7 = *(const uint4*)(gB1 + t + 1536); } while (0)

#define STOREG() do { u16* D = W + lane * 8;                                         \
    *(uint4*)(D +    0) = a0; *(uint4*)(D +  512) = a1;                              \
    *(uint4*)(D + 1024) = a2; *(uint4*)(D + 1536) = a3;                              \
    *(uint4*)(D + 2048) = b0; *(uint4*)(D + 2560) = b1;                              \
    *(uint4*)(D + 3072) = b2; *(uint4*)(D + 3584) = b3;                              \
    *(uint4*)(D + 4096) = b4; *(uint4*)(D + 4608) = b5;                              \
    *(uint4*)(D + 5120) = b6; *(uint4*)(D + 5632) = b7; } while (0)

    LOADG(0);
    STOREG();
    LOADG(1);

    const int NT = Kd >> 5;
    for (int kt = 0; kt < NT; ++kt) {
        f16x8 fah[4], fbh[8];
        #pragma unroll
        for (int i = 0; i < 4; ++i)
            fah[i] = *(const f16x8*)(W + quad * 512 + (i * 16 + mr) * 8);
        #pragma unroll
        for (int j = 0; j < 8; ++j)
            fbh[j] = *(const f16x8*)(W + 2048 + ((j < 4) ? 0 : 2048)
                                     + quad * 512 + ((j & 3) * 16 + mr) * 8);
        if (kt + 1 < NT) STOREG();         // in-order DS: safe after the reads
        if (kt + 2 < NT) LOADG(kt + 2);    // stays in flight: no barrier drains
        #pragma unroll
        for (int i = 0; i < 4; ++i)
            #pragma unroll
            for (int j = 0; j < 8; ++j)
                acc[i][j] = __builtin_amdgcn_mfma_f32_16x16x32_f16(fah[i], fbh[j], acc[i][j], 0, 0, 0);
    }
#undef LOADG
#undef STOREG

    if (n0 < 1024) {
        // Q half: relu -> fp32 write + fused sig partials
        #pragma unroll
        for (int i = 0; i < 4; ++i)
            #pragma unroll
            for (int j = 0; j < 8; ++j)
                #pragma unroll
                for (int r = 0; r < 4; ++r) {
                    float v = fmaxf(acc[i][j][r], 0.f);
                    acc[i][j][r] = v;
                    int row = m0 + mw + i * 16 + quad * 4 + r;
                    int col = n0 + nw + j * 16 + mr;
                    Qf[(long)row * 1024 + col] = v;
                }
        int slot = (id & 31) * 2 + (w & 1);
        #pragma unroll
        for (int j = 0; j < 8; ++j) {
            float ps = 0.f, p8 = 0.f;
            #pragma unroll
            for (int i = 0; i < 4; ++i) {
                #pragma unroll
                for (int r = 0; r < 4; ++r) ps += acc[i][j][r];
                if ((quad & 1) == 0) p8 += acc[i][j][0];   // row%8==0 rows
            }
            ps += __shfl_xor(ps, 16, 64); ps += __shfl_xor(ps, 32, 64);
            p8 += __shfl_xor(p8, 16, 64); p8 += __shfl_xor(p8, 32, 64);
            if (quad == 0) {
                int col = n0 + nw + j * 16 + mr;
                Ps [slot * 1024 + col] = ps;
                Ps8[slot * 1024 + col] = p8;
            }
        }
    } else {
        // V half: relu -> fp16 PAIR layout: (e, e+64) adjacent
        #pragma unroll
        for (int i = 0; i < 4; ++i)
            #pragma unroll
            for (int j = 0; j < 8; ++j)
                #pragma unroll
                for (int r = 0; r < 4; ++r) {
                    float v = fmaxf(acc[i][j][r], 0.f);
                    int row = m0 + mw + i * 16 + quad * 4 + r;
                    int vcol = n0 - 1024 + nw + j * 16 + mr;
                    int pa = (vcol & ~127) + ((vcol & 63) * 2) + ((vcol >> 6) & 1);
                    Vh[(long)row * 1024 + pa] = f2h(v);
                }
    }
}

// ---------------------------------------------------------------------------
// gemm_dec v14 (REVERTED): register-staged 128x128 tile, barrier-free.
// ---------------------------------------------------------------------------
__global__ __launch_bounds__(256, 1) void gemm_dec(
    const u16* __restrict__ Ah, const u16* __restrict__ Bh,
    float* __restrict__ C, int N, int Kd)
{
    __shared__ __align__(16) u16 S[4][4096];   // 8 KB per wave

    const int tid  = threadIdx.x;
    const int w    = tid >> 6;
    const int lane = tid & 63;

    const int id   = blockIdx.x;
    const int m0   = (((id & 7) << 2) + ((id >> 3) & 3)) * 128;
    const int n0   = (id >> 5) * 128;

    const int mw   = (w & 1) * 64, nw = (w >> 1) * 64;
    const int mr   = lane & 15, quad = lane >> 4;

    const long sstr = (long)Kd * 64;
    const u16* gAh = Ah + (long)((m0 + mw) >> 6) * sstr;
    const u16* gBh = Bh + (long)((n0 + nw) >> 6) * sstr;

    u16* W = &S[w][0];   // [A:4][B:4] x [kq][row64][8] u16

    f32x4 acc[4][4] = {};
    uint4 a0, a1, a2, a3, b0, b1, b2, b3;

#define LOADG(KT) do { long t = (long)(KT) * 2048 + lane * 8;                        \
    a0 = *(const uint4*)(gAh + t +    0); a1 = *(const uint4*)(gAh + t +  512);      \
    a2 = *(const uint4*)(gAh + t + 1024); a3 = *(const uint4*)(gAh + t + 1536);      \
    b0 = *(const uint4*)(gBh + t +    0); b1 = *(const uint4*)(gBh + t +  512);      \
    b2 = *(const uint4*)(gBh + t + 1024); b3 = *(const uint4*)(gBh + t + 1536); } while (0)

#define STOREG() do { u16* D = W + lane * 8;                                         \
    *(uint4*)(D +    0) = a0; *(uint4*)(D +  512) = a1;                              \
    *(uint4*)(D + 1024) = a2; *(uint4*)(D + 1536) = a3;                              \
    *(uint4*)(D + 2048) = b0; *(uint4*)(D + 2560) = b1;                              \
    *(uint4*)(D + 3072) = b2; *(uint4*)(D + 3584) = b3; } while (0)

    LOADG(0);
    STOREG();
    LOADG(1);

    const int NT = Kd >> 5;
    for (int kt = 0; kt < NT; ++kt) {
        f16x8 fah[4], fbh[4];
        #pragma unroll
        for (int i = 0; i < 4; ++i) {
            int ro = quad * 512 + (i * 16 + mr) * 8;
            fah[i] = *(const f16x8*)(W + ro);
            fbh[i] = *(const f16x8*)(W + 2048 + ro);
        }
        if (kt + 1 < NT) STOREG();
        if (kt + 2 < NT) LOADG(kt + 2);
        #pragma unroll
        for (int i = 0; i < 4; ++i)
            #pragma unroll
            for (int j = 0; j < 4; ++j)
                acc[i][j] = __builtin_amdgcn_mfma_f32_16x16x32_f16(fah[i], fbh[j], acc[i][j], 0, 0, 0);
    }
#undef LOADG
#undef STOREG

    #pragma unroll
    for (int i = 0; i < 4; ++i)
        #pragma unroll
        for (int j = 0; j < 4; ++j)
            #pragma unroll
            for (int r = 0; r < 4; ++r) {
                int row = m0 + mw + i * 16 + quad * 4 + r;
                int col = n0 + nw + j * 16 + mr;
                C[(long)row * N + col] = acc[i][j][r];
            }
}

// ---------------------------------------------------------------------------
// qu_stage v14: fused metric finish + Q->Qbf/U/|u|^2 (unchanged).
// ---------------------------------------------------------------------------
__global__ __launch_bounds__(256) void qu_stage(const float* __restrict__ Qf,
                                                const float* __restrict__ Pm2,
                                                const float* __restrict__ b2,
                                                const float* __restrict__ base,
                                                u16* __restrict__ Qbf,
                                                u16* __restrict__ Uh, u16* __restrict__ Ul,
                                                float* __restrict__ nArr)
{
    __shared__ float sMe[128];
    const int tid = threadIdx.x;
    const int bh  = blockIdx.x >> 8;          // 256 blocks per bh
    if (tid < 128) {
        int b = bh >> 3;
        int c = (bh & 7) * 128 + tid;
        float a = b2[c];
        #pragma unroll
        for (int kc = 0; kc < 16; ++kc)
            a += Pm2[(b * 16 + kc) * 1024 + c];
        float mv = base[c] + 0.1f * a;
        sMe[tid] = fmaxf(mv, 0.f) + log1pf(expf(-fabsf(mv)));
    }
    __syncthreads();

    int gid4 = (blockIdx.x * 256 + tid) * 4;   // over 2*8*2048*128
    int e4 = gid4 & 127;
    int t  = (gid4 >> 7) & 2047;
    int b  = bh >> 3, h = bh & 7;
    float4 q = *(const float4*)&Qf[((long)(b * 2048 + t)) * 1024 + h * 128 + e4];
    ushort4 qo = {f2bf(q.x), f2bf(q.y), f2bf(q.z), f2bf(q.w)};
    *(ushort4*)&Qbf[((long)(b * 2048 + t)) * 1024 + h * 128 + e4] = qo;

    float4 m = *(const float4*)&sMe[e4];
    float ux = sqrtf(m.x) * q.x, uy = sqrtf(m.y) * q.y;
    float uz = sqrtf(m.z) * q.z, uw = sqrtf(m.w) * q.w;
    u16 h0, l0, h1, l1, h2, l2, h3, l3;
    split1h(ux, h0, l0); split1h(uy, h1, l1);
    split1h(uz, h2, l2); split1h(uw, h3, l3);
    ushort4 hv = {h0, h1, h2, h3}, lv = {l0, l1, l2, l3};
    *(ushort4*)&Uh[gid4] = hv;
    *(ushort4*)&Ul[gid4] = lv;
    float ps = ux * ux + uy * uy + uz * uz + uw * uw;
    #pragma unroll
    for (int mm = 16; mm; mm >>= 1) ps += __shfl_xor(ps, mm, 64);
    if ((tid & 31) == 0) nArr[gid4 >> 7] = ps;
}

// ---------------------------------------------------------------------------
// hebdist: merged heb_gemm (blocks 0..255) + dist_gemm (blocks 256..767).
// ---------------------------------------------------------------------------
__global__ __launch_bounds__(256, 1) void hebdist(
    const u16* __restrict__ Qbf, const u16* __restrict__ MhT,
    u16* __restrict__ HEBbf,
    const u16* __restrict__ Uh, const u16* __restrict__ Ul,
    const float* __restrict__ nArr, float* __restrict__ band)
{
    __shared__ __align__(16) u16 sA[4][128][8], sB[4][128][8];      // heb
    __shared__ __align__(16) u16 sAh[4][64][8],  sAl[4][64][8];     // dist
    __shared__ __align__(16) u16 sBh[4][128][8], sBl[4][128][8];
    __shared__ float epi[4][16][128];

    const int tid  = threadIdx.x;
    const int w    = tid >> 6;
    const int lane = tid & 63;
    const int mr   = lane & 15, quad = lane >> 4;

    if (blockIdx.x < 256) {
        // ---------------- heb_gemm body ----------------
        const int m0 = (blockIdx.x & 31) * 128;
        const int h  = blockIdx.x >> 5;
        const int mw = w * 32;
        const u16* Bm = MhT + h * 16384;

        f32x4 acc[2][8] = {};

        for (int k0 = 0; k0 < 128; k0 += 32) {
            #pragma unroll
            for (int u = 0; u < 4; ++u) {
                int c = (w & 1) * 4 + u;
                int kq = c >> 1, half = c & 1;
                const u16* src; u16* dst; long gofs;
                if (w < 2) {
                    src = Qbf;
                    dst = &sA[0][0][0] + kq * 1024 + half * 512;
                    gofs = (long)(m0 + half * 64 + lane) * 1024 + h * 128 + k0 + kq * 8;
                } else {
                    src = Bm;
                    dst = &sB[0][0][0] + kq * 1024 + half * 512;
                    gofs = (long)(half * 64 + lane) * 128 + k0 + kq * 8;
                }
                GLD16(src + gofs, dst);
            }
            __syncthreads();

            bf16x8 fa[2], fb[8];
            #pragma unroll
            for (int i = 0; i < 2; ++i)
                fa[i] = *(const bf16x8*)&sA[quad][mw + i * 16 + mr][0];
            #pragma unroll
            for (int j = 0; j < 8; ++j)
                fb[j] = *(const bf16x8*)&sB[quad][j * 16 + mr][0];
            #pragma unroll
            for (int i = 0; i < 2; ++i)
                #pragma unroll
                for (int j = 0; j < 8; ++j)
                    acc[i][j] = __builtin_amdgcn_mfma_f32_16x16x32_bf16(fa[i], fb[j], acc[i][j], 0, 0, 0);
            __syncthreads();
        }

        #pragma unroll
        for (int i = 0; i < 2; ++i)
            #pragma unroll
            for (int j = 0; j < 8; ++j)
                #pragma unroll
                for (int r = 0; r < 4; ++r) {
                    int row = m0 + mw + i * 16 + quad * 4 + r;
                    int col = h * 128 + j * 16 + mr;
                    HEBbf[(long)row * 1024 + col] = f2bf(acc[i][j][r]);
                }
    } else {
        // ---------------- dist_gemm body ----------------
        const int bid  = blockIdx.x - 256;
        const int tile = bid & 31, bh = bid >> 5;
        const int t0   = tile * 64;
        const long ub  = (long)bh * 2048 * 128;

        const u16 *s0, *s1, *s2, *s3, *s4, *s5;
        u16 *d0, *d1, *d2, *d3, *d4, *d5;
        long o0, o1, o2, o3, o4, o5;
        {
            auto mk = [&](int i, const u16*& src, u16*& dst, long& ofs) {
                int c = i * 256 + tid;
                if (c < 512) {
                    int row = c & 63, kq = (c >> 6) & 3;
                    src = (c < 256) ? Uh : Ul;
                    ofs = ub + (long)(t0 + row) * 128 + kq * 8;
                    dst = ((c < 256) ? &sAh[0][0][0] : &sAl[0][0][0]) + kq * 512 + row * 8;
                } else {
                    int cb = c - 512;
                    int row = cb & 127, kq = (cb >> 7) & 3;
                    src = (cb < 512) ? Uh : Ul;
                    ofs = ub + (long)(t0 - 64 + row) * 128 + kq * 8;
                    dst = ((cb < 512) ? &sBh[0][0][0] : &sBl[0][0][0]) + kq * 1024 + row * 8;
                }
            };
            mk(0, s0, d0, o0); mk(1, s1, d1, o1); mk(2, s2, d2, o2);
            mk(3, s3, d3, o3); mk(4, s4, d4, o4); mk(5, s5, d5, o5);
        }

        f32x4 acc[8] = {};
        uint4 g0, g1, g2, g3, g4, g5;
        g0 = *(const uint4*)(s0 + o0); g1 = *(const uint4*)(s1 + o1);
        g2 = *(const uint4*)(s2 + o2); g3 = *(const uint4*)(s3 + o3);
        g4 = *(const uint4*)(s4 + o4); g5 = *(const uint4*)(s5 + o5);

        for (int k0 = 0; k0 < 128; k0 += 32) {
            *(uint4*)d0 = g0; *(uint4*)d1 = g1; *(uint4*)d2 = g2;
            *(uint4*)d3 = g3; *(uint4*)d4 = g4; *(uint4*)d5 = g5;
            __syncthreads();

            if (k0 + 32 < 128) {
                int kn = k0 + 32;
                g0 = *(const uint4*)(s0 + o0 + kn); g1 = *(const uint4*)(s1 + o1 + kn);
                g2 = *(const uint4*)(s2 + o2 + kn); g3 = *(const uint4*)(s3 + o3 + kn);
                g4 = *(const uint4*)(s4 + o4 + kn); g5 = *(const uint4*)(s5 + o5 + kn);
            }

            f16x8 fah = *(const f16x8*)&sAh[quad][w * 16 + mr][0];
            f16x8 fal = *(const f16x8*)&sAl[quad][w * 16 + mr][0];
            #pragma unroll
            for (int j = 0; j < 8; ++j) {
                f16x8 fbh = *(const f16x8*)&sBh[quad][j * 16 + mr][0];
                f16x8 fbl = *(const f16x8*)&sBl[quad][j * 16 + mr][0];
                acc[j] = __builtin_amdgcn_mfma_f32_16x16x32_f16(fah, fbh, acc[j], 0, 0, 0);
                acc[j] = __builtin_amdgcn_mfma_f32_16x16x32_f16(fah, fbl, acc[j], 0, 0, 0);
                acc[j] = __builtin_amdgcn_mfma_f32_16x16x32_f16(fal, fbh, acc[j], 0, 0, 0);
            }
            __syncthreads();
        }

        #pragma unroll
        for (int j = 0; j < 8; ++j)
            #pragma unroll
            for (int r = 0; r < 4; ++r)
                epi[w][quad * 4 + r][j * 16 + mr] = acc[j][r];
        __syncthreads();

        const float* nb = nArr + (long)bh * 2048;
        #pragma unroll
        for (int i = 0; i < 16; ++i) {
            int id = i * 256 + tid;
            int tl = id >> 6, j = id & 63;
            int t  = t0 + tl;
            int r  = t - j;
            int rc = r < 0 ? 0 : r;
            int rl = tl - j + 64;
            float S  = epi[tl >> 4][tl & 15][rl];
            float d2 = nb[t] + nb[rc] - 2.0f * S;
            band[((long)bh * 2048 + t) * 64 + j] = d2;
        }
    }
}

// ---------------------------------------------------------------------------
// mlp chain (unchanged).
// ---------------------------------------------------------------------------
__global__ __launch_bounds__(256) void mlp1_part(const float* __restrict__ Ps,
                                                 const float* __restrict__ Ps8,
                                                 const float* __restrict__ w1,
                                                 float* __restrict__ Pm)
{
    __shared__ float ssig[32];
    int tid = threadIdx.x;
    int o  = blockIdx.x * 256 + tid;           // 0..511
    int b  = blockIdx.y;
    int kc = blockIdx.z;                       // 0..31
    int k0 = kc * 32;
    if (tid < 32) {
        int k = k0 + tid;
        float s = 0.f, s8 = 0.f;
        #pragma unroll
        for (int ms = 0; ms < 32; ++ms) {
            long po = ((long)(b * 32 + ms)) * 1024 + k;
            s  += Ps[po];
            s8 += Ps8[po];
        }
        ssig[tid] = s * (1.0f / 2048.0f) + 0.5f * s8 * (1.0f / 256.0f);
    }
    __syncthreads();
    float a = 0.f;
    #pragma unroll 8
    for (int kk = 0; kk < 32; ++kk)
        a += ssig[kk] * w1[(long)(k0 + kk) * 512 + o];
    Pm[((b * 32) + kc) * 512 + o] = a;
}

__global__ __launch_bounds__(256) void mlp2_part(const float* __restrict__ Pm1,
                                                 const float* __restrict__ b1,
                                                 const float* __restrict__ w2,
                                                 float* __restrict__ Pm)
{
    __shared__ float sH[32];
    int tid = threadIdx.x;
    int c  = blockIdx.x * 256 + tid;           // 0..1023
    int b  = blockIdx.y;
    int kc = blockIdx.z;                       // 0..15
    int k0 = kc * 32;
    if (tid < 32) {
        int o = k0 + tid;
        float a = b1[o];
        #pragma unroll
        for (int kcc = 0; kcc < 32; ++kcc)
            a += Pm1[(b * 32 + kcc) * 512 + o];
        sH[tid] = 0.5f * a * (1.0f + erff(a * 0.70710678118f));
    }
    __syncthreads();
    float a = 0.f;
    #pragma unroll 8
    for (int kk = 0; kk < 32; ++kk)
        a += sH[kk] * w2[(long)(k0 + kk) * 1024 + c];
    Pm[((b * 16) + kc) * 1024 + c] = a;
}

// ---------------------------------------------------------------------------
// Context kernel v10: paired V gather with MAX MLP — all 32 gather loads
// issued before accumulation (statically indexed regs, ~32 extra VGPR).
// Round-1 PMC showed this kernel latency-bound (0 Mfma / 60% VALU / 21% HBM).
// ---------------------------------------------------------------------------
__global__ __launch_bounds__(256) void context_k(
    const float* __restrict__ Qf, const u16* __restrict__ Vh,
    const float* __restrict__ band, const u16* __restrict__ HEBbf,
    u16* __restrict__ CTh)
{
    __shared__ float wv[4][32];
    __shared__ int   wi[4][32];

    const int w    = threadIdx.x >> 6;
    const int lane = threadIdx.x & 63;
    const int gw   = blockIdx.x * 4 + w;
    const int h    = gw & 7;
    const int bt   = gw >> 3;
    const int t    = bt & (T_ - 1);
    const int b    = bt >> 11;
    const int bh   = b * 8 + h;

    const long qrow  = (long)bt * 1024 + h * 128;
    const long hrow  = (long)bt * 1024 + h * 128;

    float q0 = Qf[qrow + lane], q1 = Qf[qrow + 64 + lane];
    float ss = q0 * q0 + q1 * q1;
    #pragma unroll
    for (int s = 32; s; s >>= 1) ss += __shfl_xor(ss, s, 64);
    const float qn  = sqrtf(ss);
    const float inv = 1.0f / fmaxf(qn, 1e-12f);

    int je = lane < t ? lane : t;
    float d2v = (je == 0) ? 0.f
              : band[((long)bh * 2048 + t) * 64 + je];
    float d2f = fmaxf(d2v, 0.f) + 1e-8f;                 // > 0
    unsigned kb = (__float_as_uint(d2f) & 0xFFFFFFC0u) | (unsigned)lane;

    // bitonic construction to k=32: lanes 0-31 ascending, 32-63 descending
    #pragma unroll
    for (int k = 2; k <= 32; k <<= 1)
        #pragma unroll
        for (int s = k >> 1; s >= 1; s >>= 1) {
            unsigned ok = __shfl_xor(kb, s, 64);
            bool takeMin = (((lane & k) == 0) == ((lane & s) == 0));
            if ((ok < kb) == takeMin) kb = ok;           // keys unique: no ties
        }
    // cross-half min: lanes 0-31 now hold the 32 smallest (set, unsorted)
    {
        unsigned ok = __shfl_xor(kb, 32, 64);
        kb = ok < kb ? ok : kb;
    }

    int jj = kb & 63;
    float wexp = 0.f;
    if (lane < 32)
        wexp = expf(-sqrtf(__uint_as_float(kb & 0xFFFFFFC0u)));
    float tot = wexp;
    #pragma unroll
    for (int s = 32; s; s >>= 1) tot += __shfl_xor(tot, s, 64);
    float wn = wexp / (tot + 1e-8f);
    if (lane < 32) {
        wv[w][lane] = wn;
        int ii = t - jj; if (ii < 0) ii = 0;
        wi[w][lane] = ii;
    }

    // phase 1: issue ALL 32 gather loads (32 outstanding, fully unrolled)
    unsigned vv[32];
    #pragma unroll
    for (int k = 0; k < 32; ++k) {
        long vb = ((long)(b * T_ + wi[w][k])) * 1024 + h * 128 + lane * 2;
        vv[k] = *(const unsigned*)&Vh[vb];
    }
    // phase 2: accumulate
    float c0 = 0.f, c1 = 0.f;
    #pragma unroll
    for (int k = 0; k < 32; ++k) {
        float wk = wv[w][k];
        c0 += wk * h2f((u16)(vv[k] & 0xffffu));   // element e = lane
        c1 += wk * h2f((u16)(vv[k] >> 16));       // element e = lane + 64
    }

    if (qn > 0.2f) {
        float s = 0.1f * inv;
        c0 += s * bf2f(HEBbf[hrow + lane]);
        c1 += s * bf2f(HEBbf[hrow + 64 + lane]);
    }

    // packed CT write (Kd=1024 -> strip stride 65536): col c = h*128+lane(+64)
    int c0c = h * 128 + lane, c1c = c0c + 64;
    long po0 = (long)(bt >> 6) * 65536 + (c0c >> 5) * 2048
             + ((c0c >> 3) & 3) * 512 + (bt & 63) * 8 + (c0c & 7);
    long po1 = (long)(bt >> 6) * 65536 + (c1c >> 5) * 2048
             + ((c1c >> 3) & 3) * 512 + (bt & 63) * 8 + (c1c & 7);
    CTh[po0] = f2h(q0 * c0);
    CTh[po1] = f2h(q1 * c1);
}

// ---------------------------------------------------------------------------
extern "C" void kernel_launch(void* const* d_in, const int* in_sizes, int n_in,
                              void* d_out, int out_size, void* d_ws, size_t ws_size,
                              hipStream_t stream)
{
    const float* x     = (const float*)d_in[0];
    const float* enc_q = (const float*)d_in[1];
    const float* enc_v = (const float*)d_in[2];
    const float* w1    = (const float*)d_in[3];
    const float* b1    = (const float*)d_in[4];
    const float* w2    = (const float*)d_in[5];
    const float* b2    = (const float*)d_in[6];
    const float* base  = (const float*)d_in[7];
    const float* hU    = (const float*)d_in[8];
    const float* hV    = (const float*)d_in[9];
    const float* dec   = (const float*)d_in[10];
    float* out = (float*)d_out;
    float* ws  = (float*)d_ws;

    // ws (fp32-offset map), peak 13205504 floats = 50.4 MB (< 51 MB budget):
    float* Qf   = ws;                       // [0, 4194304)       gemm_qv -> qu/context
    u16*  Vhp   = (u16*)(ws + 4194304);     // [4194304, 6291456) pair-layout V
    float* band = ws + 6291456;             // [6291456, 8388608) dist -> context
    u16*  wTh   = (u16*)(ws + 8388608);     // enc weights, dead after gemm_qv
    u16*  Ulp   = (u16*)(ws + 8388608);     // U lo, after wTh/Ps dead
    float* Ps   = ws + 9961472;             // sig partials, dead after mlp1
    float* Ps8  = ws + 10027008;
    u16*  Uhp   = (u16*)(ws + 10485760);    // U hi [10485760, 12582912)
    u16*  CTh   = (u16*)(ws + 8388608);     // packed CT, after Ul dead
    u16*  MhT   = (u16*)(ws + 12582912);    // [12582912, 12648448)
    float* nA   = ws + 12648448;            // [12648448, 12681216)
    u16*  wdTh  = (u16*)(ws + 12681216);    // [12681216, 13205504) decoder W
    u16*  xh    = (u16*)d_out;              // packed x staging in d_out
    u16*  Qbf   = (u16*)d_out;              // after xh dead; dead after hebdist
    u16*  HEBbf = (u16*)d_out + 4194304;    // float [2097152, 4194304)
    float* Pm1  = (float*)d_out + 2097152;  // dead before hebdist writes HEBbf
    float* Pm2  = (float*)d_out + 2129920;

    // 1. all input-only conversions (x, enc, dec, hebb matrices)
    cvt_in<<<7680, 256, 0, stream>>>(x, enc_q, enc_v, dec, hU, hV,
                                     xh, wTh, wdTh, MhT);

    // 2. QV = relu(x @ [enc_q | enc_v]) -> Q fp32 + V fp16 pairs + sig partials
    gemm_qv<<<256, 256, 0, stream>>>(xh, wTh, Qf, Vhp, Ps, Ps8, 1024);

    // 3-4. metric MLP split-K
    mlp1_part<<<dim3(2, 2, 32), 256, 0, stream>>>(Ps, Ps8, w1, Pm1);
    mlp2_part<<<dim3(4, 2, 16), 256, 0, stream>>>(Pm1, b1, w2, Pm2);

    // 5. Q -> Qbf/U/|u|^2 with fused metric finish
    qu_stage<<<4096, 256, 0, stream>>>(Qf, Pm2, b2, base, Qbf, Uhp, Ulp, nA);

    // 6. merged HEB gemm + banded distance gemm
    hebdist<<<768, 256, 0, stream>>>(Qbf, MhT, HEBbf, Uhp, Ulp, nA, band);

    // 7. top-32 select + weighted V gather + Hebb term -> CT fp16 packed
    context_k<<<8192, 256, 0, stream>>>(Qf, Vhp, band, HEBbf, CTh);

    // 8. out = CT @ decoder
    gemm_dec<<<256, 256, 0, stream>>>(CTh, wdTh, out, 1024, 1024);
}